// Round 1
// baseline (863.463 us; speedup 1.0000x reference)
//
#include <hip/hip_runtime.h>

// ---------------------------------------------------------------- types
typedef __bf16  bf16x8 __attribute__((ext_vector_type(8)));
typedef float   f32x4  __attribute__((ext_vector_type(4)));

typedef const __attribute__((address_space(1))) void* gas_p;
typedef __attribute__((address_space(3))) void*       las_p;

__device__ __forceinline__ void glds16(const void* g, void* l) {
  // global -> LDS direct, 16B per lane; LDS dst is wave-uniform base + lane*16
  __builtin_amdgcn_global_load_lds((gas_p)g, (las_p)l, 16, 0, 0);
}

__device__ __forceinline__ ushort f2bf(float f) {  // RNE float->bf16 (bit-exact, no header drift)
  unsigned u = __float_as_uint(f);
  u += 0x7fffu + ((u >> 16) & 1u);
  return (ushort)(u >> 16);
}

// ---------------------------------------------------------------- weight cast + transpose  w[K][N] f32 -> wT[N][K] bf16
__global__ __launch_bounds__(256) void castT_k(const float* __restrict__ w,
                                               ushort* __restrict__ wT,
                                               const int Kd, const int Nd) {
  __shared__ float t[32][33];
  const int nb = blockIdx.x * 32, kb = blockIdx.y * 32;
  const int tx = threadIdx.x & 31, ty = threadIdx.x >> 5;  // 32 x 8
#pragma unroll
  for (int r = 0; r < 32; r += 8)
    t[ty + r][tx] = w[(size_t)(kb + ty + r) * Nd + nb + tx];
  __syncthreads();
#pragma unroll
  for (int r = 0; r < 32; r += 8)
    wT[(size_t)(nb + ty + r) * Kd + kb + tx] = f2bf(t[tx][ty + r]);
}

// ---------------------------------------------------------------- LayerNorm (d=1024), fp32 in -> bf16 out
__global__ __launch_bounds__(256) void ln_k(const float* __restrict__ x,
                                            const float* __restrict__ gam,
                                            const float* __restrict__ bet,
                                            ushort* __restrict__ out) {
  const int row = blockIdx.x, tid = threadIdx.x;
  const float4 v = ((const float4*)(x + (size_t)row * 1024))[tid];
  float s  = v.x + v.y + v.z + v.w;
  float sq = v.x * v.x + v.y * v.y + v.z * v.z + v.w * v.w;
#pragma unroll
  for (int o = 32; o > 0; o >>= 1) { s += __shfl_xor(s, o); sq += __shfl_xor(sq, o); }
  __shared__ float red[8];
  const int wid = tid >> 6, lane = tid & 63;
  if (lane == 0) { red[wid] = s; red[4 + wid] = sq; }
  __syncthreads();
  s  = red[0] + red[1] + red[2] + red[3];
  sq = red[4] + red[5] + red[6] + red[7];
  const float mu   = s * (1.0f / 1024.0f);
  const float var  = sq * (1.0f / 1024.0f) - mu * mu;
  const float rstd = rsqrtf(var + 1e-5f);
  const float4 gv = ((const float4*)gam)[tid];
  const float4 bv = ((const float4*)bet)[tid];
  ushort4 o4;
  o4.x = f2bf((v.x - mu) * rstd * gv.x + bv.x);
  o4.y = f2bf((v.y - mu) * rstd * gv.y + bv.y);
  o4.z = f2bf((v.z - mu) * rstd * gv.z + bv.z);
  o4.w = f2bf((v.w - mu) * rstd * gv.w + bv.w);
  ((ushort4*)(out + (size_t)row * 1024))[tid] = o4;
}

// ---------------------------------------------------------------- V [B,H,T,64] -> Vt [B,H,64,T]  (bf16)
__global__ __launch_bounds__(256) void vtrans_k(const ushort* __restrict__ Vn,
                                                ushort* __restrict__ Vt) {
  const int bh = blockIdx.y, i0 = blockIdx.x * 64, tid = threadIdx.x;
  __shared__ ushort t[64][65];
  const ushort* src = Vn + (size_t)bh * (2048 * 64);
#pragma unroll
  for (int kk = 0; kk < 16; ++kk) {
    const int e = tid + kk * 256, r = e >> 6, c = e & 63;
    t[r][c] = src[(size_t)(i0 + r) * 64 + c];
  }
  __syncthreads();
  ushort* dst = Vt + (size_t)bh * (64 * 2048);
#pragma unroll
  for (int kk = 0; kk < 16; ++kk) {
    const int e = tid + kk * 256, r = e >> 6, c = e & 63;  // r = dh, c = i
    dst[(size_t)r * 2048 + i0 + c] = t[c][r];
  }
}

// ---------------------------------------------------------------- GEMM: A[M][K] bf16 x Bt[N][K] bf16 -> epilogue
// 128x128 tile, 4 waves (2x2), BK=32, global_load_lds staging (m97 structure).
// EPI: 0 = QKV (bias+RoPE+scale, scatter to Q/K/V [B,H,T,64])
//      1 = PROJ/MLP2 style fp32 out (+bias +resid)
//      2 = GELU -> bf16 out
template <int EPI>
__global__ __launch_bounds__(256) void gemm_k(
    const ushort* __restrict__ A, const ushort* __restrict__ Bt,
    const int M, const int N, const int K,
    const float* __restrict__ bias,
    const float* __restrict__ resid,
    float* __restrict__ outf,
    ushort* __restrict__ outb,
    ushort* __restrict__ qo, ushort* __restrict__ ko, ushort* __restrict__ vo) {
  __shared__ ushort lA[128 * 32];
  __shared__ ushort lB[128 * 32];
  const int tid = threadIdx.x;
  const int wid = tid >> 6, lane = tid & 63;
  const int l15 = lane & 15, g = lane >> 4;
  const int m0 = blockIdx.y * 128, n0 = blockIdx.x * 128;
  const int wm = wid >> 1, wn = wid & 1;

  // staging map: chunk q = wid (+4) -> rows q*16 + lane/4, cols (lane&3)*8
  const int srow = wid * 16 + (lane >> 2);
  const int scol = (lane & 3) * 8;
  const ushort* Ag0 = A + (size_t)(m0 + srow) * K + scol;
  const ushort* Ag1 = Ag0 + (size_t)64 * K;
  const ushort* Bg0 = Bt + (size_t)(n0 + srow) * K + scol;
  const ushort* Bg1 = Bg0 + (size_t)64 * K;
  ushort* lA0 = &lA[wid * 512];
  ushort* lA1 = &lA[(wid + 4) * 512];
  ushort* lB0 = &lB[wid * 512];
  ushort* lB1 = &lB[(wid + 4) * 512];

  const ushort* lar = &lA[(wm * 64 + l15) * 32 + g * 8];
  const ushort* lbr = &lB[(wn * 64 + l15) * 32 + g * 8];

  f32x4 acc[4][4] = {};

  for (int kt = 0; kt < K; kt += 32) {
    glds16(Ag0 + kt, lA0);
    glds16(Ag1 + kt, lA1);
    glds16(Bg0 + kt, lB0);
    glds16(Bg1 + kt, lB1);
    __syncthreads();  // drains vmcnt before barrier -> staging visible
    bf16x8 af[4], bfr[4];
#pragma unroll
    for (int m = 0; m < 4; ++m) af[m] = *(const bf16x8*)(lar + m * 16 * 32);
#pragma unroll
    for (int n = 0; n < 4; ++n) bfr[n] = *(const bf16x8*)(lbr + n * 16 * 32);
#pragma unroll
    for (int m = 0; m < 4; ++m)
#pragma unroll
      for (int n = 0; n < 4; ++n)
        acc[m][n] = __builtin_amdgcn_mfma_f32_16x16x32_bf16(af[m], bfr[n], acc[m][n], 0, 0, 0);
    __syncthreads();
  }

  const int rb = m0 + wm * 64;
  const int cb = n0 + wn * 64;
  if constexpr (EPI == 0) {
    // QKV: c = which*1024 + h*64 + dd ; rope pairs (dd, dd+32) live in frags (n, n+2)
#pragma unroll
    for (int m = 0; m < 4; ++m)
#pragma unroll
      for (int r = 0; r < 4; ++r) {
        const int s = rb + m * 16 + g * 4 + r;
        const int bb = s >> 11, ii = s & 2047;
#pragma unroll
        for (int n = 0; n < 2; ++n) {
          const int c = cb + n * 16 + l15;
          const int which = c >> 10, h = (c >> 6) & 15, dd = c & 63;  // dd < 32
          const float vlo = acc[m][n][r] + bias[c];
          const float vhi = acc[m][n + 2][r] + bias[c + 32];
          const size_t off = ((size_t)((bb * 16 + h) * 2048 + ii)) * 64;
          if (which == 2) {
            vo[off + dd]      = f2bf(vlo);
            vo[off + dd + 32] = f2bf(vhi);
          } else {
            const float fr = __expf(-0.29710776f * (float)dd);  // 10000^(-dd/31)
            const float ang = (float)ii * fr;
            const float c0 = cosf(ang), s0 = sinf(ang);
            float rlo = vlo * c0 - vhi * s0;
            float rhi = vhi * c0 + vlo * s0;
            if (which == 0) { rlo *= 0.125f; rhi *= 0.125f; }  // fold attn scale into Q
            ushort* dst = (which == 0) ? qo : ko;
            dst[off + dd]      = f2bf(rlo);
            dst[off + dd + 32] = f2bf(rhi);
          }
        }
      }
  } else {
#pragma unroll
    for (int m = 0; m < 4; ++m)
#pragma unroll
      for (int n = 0; n < 4; ++n)
#pragma unroll
        for (int r = 0; r < 4; ++r) {
          const int row = rb + m * 16 + g * 4 + r;
          const int col = cb + n * 16 + l15;
          float v = acc[m][n][r] + bias[col];
          if constexpr (EPI == 1) {  // fp32 out: + residual
            v += resid[(size_t)row * N + col];
            outf[(size_t)row * N + col] = v;
          } else {  // EPI==2: exact GELU -> bf16
            const float ge = 0.5f * v * (1.0f + erff(v * 0.70710678f));
            outb[(size_t)row * N + col] = f2bf(ge);
          }
        }
  }
}

// ---------------------------------------------------------------- flash attention, 1 wave per 16 q-rows
// Q,K: [B,H,T,64] bf16 (Q pre-scaled by 1/8, RoPE applied). Vt: [B,H,64,T] bf16.
// O: [B,T,H*64] bf16.
__global__ __launch_bounds__(64) void attn_k(const ushort* __restrict__ Q,
                                             const ushort* __restrict__ K,
                                             const ushort* __restrict__ Vt,
                                             ushort* __restrict__ O) {
  const int qt = blockIdx.x, bh = blockIdx.y;
  const int lane = threadIdx.x, l15 = lane & 15, g = lane >> 4;
  const int q0 = qt * 16;
  const size_t bho = (size_t)bh * (2048 * 64);
  const ushort* Qb = Q + bho;
  const ushort* Kb = K + bho;
  const ushort* Vb = Vt + bho;

  const bf16x8 qf0 = *(const bf16x8*)&Qb[(size_t)(q0 + l15) * 64 + g * 8];
  const bf16x8 qf1 = *(const bf16x8*)&Qb[(size_t)(q0 + l15) * 64 + 32 + g * 8];

  f32x4 o[4] = {};                       // PV accum: row=(g*4+r)=q, col=l15 within dh frag nf
  float mrow[4] = {-1e30f, -1e30f, -1e30f, -1e30f};
  float lrow[4] = {0.f, 0.f, 0.f, 0.f};
  __shared__ ushort pl[16 * 40];         // P tile [16 q][32 k], row stride 40 (pad: bank spread)

  const int nkt = qt + 1;                // causal: need k-tiles 0..qt
  for (int kt0 = 0; kt0 < nkt; kt0 += 2) {
    f32x4 s[2];
#pragma unroll
    for (int sub = 0; sub < 2; ++sub) {
      const int kt = kt0 + sub;
      if (kt < nkt) {
        const int kr = kt * 16 + l15;
        const bf16x8 kf0 = *(const bf16x8*)&Kb[(size_t)kr * 64 + g * 8];
        const bf16x8 kf1 = *(const bf16x8*)&Kb[(size_t)kr * 64 + 32 + g * 8];
        f32x4 z = {0.f, 0.f, 0.f, 0.f};
        f32x4 sv = __builtin_amdgcn_mfma_f32_16x16x32_bf16(qf0, kf0, z, 0, 0, 0);
        sv = __builtin_amdgcn_mfma_f32_16x16x32_bf16(qf1, kf1, sv, 0, 0, 0);
#pragma unroll
        for (int r = 0; r < 4; ++r)
          if (kr > q0 + g * 4 + r) sv[r] = -1e30f;  // causal mask
        s[sub] = sv;
      } else {
        const f32x4 ninf = {-1e30f, -1e30f, -1e30f, -1e30f};
        s[sub] = ninf;
      }
    }
    // online softmax per q-row (row = g*4+r; 16 lanes of a group share a row-set)
#pragma unroll
    for (int r = 0; r < 4; ++r) {
      float mx = fmaxf(s[0][r], s[1][r]);
      mx = fmaxf(mx, __shfl_xor(mx, 1));
      mx = fmaxf(mx, __shfl_xor(mx, 2));
      mx = fmaxf(mx, __shfl_xor(mx, 4));
      mx = fmaxf(mx, __shfl_xor(mx, 8));
      const float mnew = fmaxf(mrow[r], mx);
      const float corr = __expf(mrow[r] - mnew);
      const float p0 = __expf(s[0][r] - mnew);
      const float p1 = __expf(s[1][r] - mnew);
      float ps = p0 + p1;
      ps += __shfl_xor(ps, 1);
      ps += __shfl_xor(ps, 2);
      ps += __shfl_xor(ps, 4);
      ps += __shfl_xor(ps, 8);
      lrow[r] = lrow[r] * corr + ps;
      mrow[r] = mnew;
#pragma unroll
      for (int nf = 0; nf < 4; ++nf) o[nf][r] *= corr;
      const int qr = g * 4 + r;
      pl[qr * 40 + l15]      = f2bf(p0);
      pl[qr * 40 + 16 + l15] = f2bf(p1);
    }
    __syncthreads();
    const bf16x8 pf = *(const bf16x8*)&pl[l15 * 40 + g * 8];  // A-frag: row=q=l15, k=g*8+j
#pragma unroll
    for (int nf = 0; nf < 4; ++nf) {
      const bf16x8 vf = *(const bf16x8*)&Vb[(size_t)(nf * 16 + l15) * 2048 + kt0 * 16 + g * 8];
      o[nf] = __builtin_amdgcn_mfma_f32_16x16x32_bf16(pf, vf, o[nf], 0, 0, 0);
    }
    __syncthreads();
  }
  const int b = bh >> 4, h = bh & 15;
#pragma unroll
  for (int nf = 0; nf < 4; ++nf)
#pragma unroll
    for (int r = 0; r < 4; ++r) {
      const int qr = q0 + g * 4 + r;
      O[((size_t)(b * 2048 + qr)) * 1024 + h * 64 + nf * 16 + l15] = f2bf(o[nf][r] / lrow[r]);
    }
}

// ---------------------------------------------------------------- launcher
extern "C" void kernel_launch(void* const* d_in, const int* in_sizes, int n_in,
                              void* d_out, int out_size, void* d_ws, size_t ws_size,
                              hipStream_t stream) {
  const float* x      = (const float*)d_in[0];
  const float* w_qkv  = (const float*)d_in[2];
  const float* b_qkv  = (const float*)d_in[3];
  const float* w_proj = (const float*)d_in[4];
  const float* b_proj = (const float*)d_in[5];
  const float* g1     = (const float*)d_in[6];
  const float* be1    = (const float*)d_in[7];
  const float* g2     = (const float*)d_in[8];
  const float* be2    = (const float*)d_in[9];
  const float* w_mlp1 = (const float*)d_in[10];
  const float* b_mlp1 = (const float*)d_in[11];
  const float* w_mlp2 = (const float*)d_in[12];
  const float* b_mlp2 = (const float*)d_in[13];

  char* ws = (char*)d_ws;
  // byte offsets (total 136.6 MB); M1 overlays Q/K/Vn/Vt (dead after attention)
  ushort* WQKVT  = (ushort*)(ws + 0);           //  6.29 MB
  ushort* WPROJT = (ushort*)(ws + 6291456);     //  2.10 MB
  ushort* WMLP1T = (ushort*)(ws + 8388608);     //  8.39 MB
  ushort* WMLP2T = (ushort*)(ws + 16777216);    //  8.39 MB
  ushort* H      = (ushort*)(ws + 25165824);    // 16.78 MB: h -> O -> h2 (sequential reuse)
  ushort* Qs     = (ushort*)(ws + 41943040);
  ushort* Ks     = (ushort*)(ws + 58720256);
  ushort* Vn     = (ushort*)(ws + 75497472);
  ushort* Vt     = (ushort*)(ws + 92274688);
  ushort* M1     = (ushort*)(ws + 41943040);    // 67.11 MB overlay
  float*  X1     = (float*)(ws + 109051904);    // 33.55 MB, ends 142606336

  // weights -> bf16 [N][K]
  castT_k<<<dim3(3072 / 32, 1024 / 32), 256, 0, stream>>>(w_qkv, WQKVT, 1024, 3072);
  castT_k<<<dim3(1024 / 32, 1024 / 32), 256, 0, stream>>>(w_proj, WPROJT, 1024, 1024);
  castT_k<<<dim3(4096 / 32, 1024 / 32), 256, 0, stream>>>(w_mlp1, WMLP1T, 1024, 4096);
  castT_k<<<dim3(1024 / 32, 4096 / 32), 256, 0, stream>>>(w_mlp2, WMLP2T, 4096, 1024);

  ln_k<<<8192, 256, 0, stream>>>(x, g1, be1, H);

  gemm_k<0><<<dim3(3072 / 128, 8192 / 128), 256, 0, stream>>>(
      H, WQKVT, 8192, 3072, 1024, b_qkv, nullptr, nullptr, nullptr, Qs, Ks, Vn);

  vtrans_k<<<dim3(32, 64), 256, 0, stream>>>(Vn, Vt);

  attn_k<<<dim3(128, 64), 64, 0, stream>>>(Qs, Ks, Vt, H /* = O */);

  gemm_k<1><<<dim3(1024 / 128, 8192 / 128), 256, 0, stream>>>(
      H, WPROJT, 8192, 1024, 1024, b_proj, x, X1, nullptr, nullptr, nullptr, nullptr);

  ln_k<<<8192, 256, 0, stream>>>(X1, g2, be2, H /* = H2 */);

  gemm_k<2><<<dim3(4096 / 128, 8192 / 128), 256, 0, stream>>>(
      H, WMLP1T, 8192, 4096, 1024, b_mlp1, nullptr, nullptr, M1, nullptr, nullptr, nullptr);

  gemm_k<1><<<dim3(1024 / 128, 8192 / 128), 256, 0, stream>>>(
      M1, WMLP2T, 8192, 1024, 4096, b_mlp2, X1, (float*)d_out, nullptr, nullptr, nullptr, nullptr);
}

// Round 2
// 788.537 us; speedup vs baseline: 1.0950x; 1.0950x over previous
//
#include <hip/hip_runtime.h>

// ---------------------------------------------------------------- types
typedef __bf16  bf16x8 __attribute__((ext_vector_type(8)));
typedef float   f32x4  __attribute__((ext_vector_type(4)));

typedef const __attribute__((address_space(1))) void* gas_p;
typedef __attribute__((address_space(3))) void*       las_p;

__device__ __forceinline__ void glds16(const void* g, void* l) {
  // global -> LDS direct, 16B per lane; LDS dst is wave-uniform base + lane*16
  __builtin_amdgcn_global_load_lds((gas_p)g, (las_p)l, 16, 0, 0);
}

__device__ __forceinline__ ushort f2bf(float f) {  // RNE float->bf16
  unsigned u = __float_as_uint(f);
  u += 0x7fffu + ((u >> 16) & 1u);
  return (ushort)(u >> 16);
}

// ---------------------------------------------------------------- weight cast + transpose  w[K][N] f32 -> wT[N][K] bf16
__global__ __launch_bounds__(256) void castT_k(const float* __restrict__ w,
                                               ushort* __restrict__ wT,
                                               const int Kd, const int Nd) {
  __shared__ float t[32][33];
  const int nb = blockIdx.x * 32, kb = blockIdx.y * 32;
  const int tx = threadIdx.x & 31, ty = threadIdx.x >> 5;  // 32 x 8
#pragma unroll
  for (int r = 0; r < 32; r += 8)
    t[ty + r][tx] = w[(size_t)(kb + ty + r) * Nd + nb + tx];
  __syncthreads();
#pragma unroll
  for (int r = 0; r < 32; r += 8)
    wT[(size_t)(nb + ty + r) * Kd + kb + tx] = f2bf(t[tx][ty + r]);
}

// ---------------------------------------------------------------- LayerNorm (d=1024), fp32 in -> bf16 out
__global__ __launch_bounds__(256) void ln_k(const float* __restrict__ x,
                                            const float* __restrict__ gam,
                                            const float* __restrict__ bet,
                                            ushort* __restrict__ out) {
  const int row = blockIdx.x, tid = threadIdx.x;
  const float4 v = ((const float4*)(x + (size_t)row * 1024))[tid];
  float s  = v.x + v.y + v.z + v.w;
  float sq = v.x * v.x + v.y * v.y + v.z * v.z + v.w * v.w;
#pragma unroll
  for (int o = 32; o > 0; o >>= 1) { s += __shfl_xor(s, o); sq += __shfl_xor(sq, o); }
  __shared__ float red[8];
  const int wid = tid >> 6, lane = tid & 63;
  if (lane == 0) { red[wid] = s; red[4 + wid] = sq; }
  __syncthreads();
  s  = red[0] + red[1] + red[2] + red[3];
  sq = red[4] + red[5] + red[6] + red[7];
  const float mu   = s * (1.0f / 1024.0f);
  const float var  = sq * (1.0f / 1024.0f) - mu * mu;
  const float rstd = rsqrtf(var + 1e-5f);
  const float4 gv = ((const float4*)gam)[tid];
  const float4 bv = ((const float4*)bet)[tid];
  ushort4 o4;
  o4.x = f2bf((v.x - mu) * rstd * gv.x + bv.x);
  o4.y = f2bf((v.y - mu) * rstd * gv.y + bv.y);
  o4.z = f2bf((v.z - mu) * rstd * gv.z + bv.z);
  o4.w = f2bf((v.w - mu) * rstd * gv.w + bv.w);
  ((ushort4*)(out + (size_t)row * 1024))[tid] = o4;
}

// ---------------------------------------------------------------- V [B,H,T,64] -> Vt [B,H,64,T]  (bf16)
__global__ __launch_bounds__(256) void vtrans_k(const ushort* __restrict__ Vn,
                                                ushort* __restrict__ Vt) {
  const int bh = blockIdx.y, i0 = blockIdx.x * 64, tid = threadIdx.x;
  __shared__ ushort t[64][65];
  const ushort* src = Vn + (size_t)bh * (2048 * 64);
#pragma unroll
  for (int kk = 0; kk < 16; ++kk) {
    const int e = tid + kk * 256, r = e >> 6, c = e & 63;
    t[r][c] = src[(size_t)(i0 + r) * 64 + c];
  }
  __syncthreads();
  ushort* dst = Vt + (size_t)bh * (64 * 2048);
#pragma unroll
  for (int kk = 0; kk < 16; ++kk) {
    const int e = tid + kk * 256, r = e >> 6, c = e & 63;  // r = dh, c = i
    dst[(size_t)r * 2048 + i0 + c] = t[c][r];
  }
}

// ---------------------------------------------------------------- GEMM: A[M][K] bf16 x Bt[N][K] bf16 -> epilogue
// 128x128 tile, 4 waves (2x2), BK=32, global_load_lds staging (m97 structure).
template <int EPI>
__global__ __launch_bounds__(256) void gemm_k(
    const ushort* __restrict__ A, const ushort* __restrict__ Bt,
    const int M, const int N, const int K,
    const float* __restrict__ bias,
    const float* __restrict__ resid,
    float* __restrict__ outf,
    ushort* __restrict__ outb,
    ushort* __restrict__ qo, ushort* __restrict__ ko, ushort* __restrict__ vo) {
  __shared__ ushort lA[128 * 32];
  __shared__ ushort lB[128 * 32];
  const int tid = threadIdx.x;
  const int wid = tid >> 6, lane = tid & 63;
  const int l15 = lane & 15, g = lane >> 4;
  const int m0 = blockIdx.y * 128, n0 = blockIdx.x * 128;
  const int wm = wid >> 1, wn = wid & 1;

  const int srow = wid * 16 + (lane >> 2);
  const int scol = (lane & 3) * 8;
  const ushort* Ag0 = A + (size_t)(m0 + srow) * K + scol;
  const ushort* Ag1 = Ag0 + (size_t)64 * K;
  const ushort* Bg0 = Bt + (size_t)(n0 + srow) * K + scol;
  const ushort* Bg1 = Bg0 + (size_t)64 * K;
  ushort* lA0 = &lA[wid * 512];
  ushort* lA1 = &lA[(wid + 4) * 512];
  ushort* lB0 = &lB[wid * 512];
  ushort* lB1 = &lB[(wid + 4) * 512];

  const ushort* lar = &lA[(wm * 64 + l15) * 32 + g * 8];
  const ushort* lbr = &lB[(wn * 64 + l15) * 32 + g * 8];

  f32x4 acc[4][4] = {};

  for (int kt = 0; kt < K; kt += 32) {
    glds16(Ag0 + kt, lA0);
    glds16(Ag1 + kt, lA1);
    glds16(Bg0 + kt, lB0);
    glds16(Bg1 + kt, lB1);
    __syncthreads();
    bf16x8 af[4], bfr[4];
#pragma unroll
    for (int m = 0; m < 4; ++m) af[m] = *(const bf16x8*)(lar + m * 16 * 32);
#pragma unroll
    for (int n = 0; n < 4; ++n) bfr[n] = *(const bf16x8*)(lbr + n * 16 * 32);
#pragma unroll
    for (int m = 0; m < 4; ++m)
#pragma unroll
      for (int n = 0; n < 4; ++n)
        acc[m][n] = __builtin_amdgcn_mfma_f32_16x16x32_bf16(af[m], bfr[n], acc[m][n], 0, 0, 0);
    __syncthreads();
  }

  const int rb = m0 + wm * 64;
  const int cb = n0 + wn * 64;
  if constexpr (EPI == 0) {
    // QKV: c = which*1024 + h*64 + dd ; rope pairs (dd, dd+32) live in frags (n, n+2)
#pragma unroll
    for (int m = 0; m < 4; ++m)
#pragma unroll
      for (int r = 0; r < 4; ++r) {
        const int s = rb + m * 16 + g * 4 + r;
        const int bb = s >> 11, ii = s & 2047;
#pragma unroll
        for (int n = 0; n < 2; ++n) {
          const int c = cb + n * 16 + l15;
          const int which = c >> 10, h = (c >> 6) & 15, dd = c & 63;  // dd < 32
          const float vlo = acc[m][n][r] + bias[c];
          const float vhi = acc[m][n + 2][r] + bias[c + 32];
          const size_t off = ((size_t)((bb * 16 + h) * 2048 + ii)) * 64;
          if (which == 2) {
            vo[off + dd]      = f2bf(vlo);
            vo[off + dd + 32] = f2bf(vhi);
          } else {
            const float fr = __expf(-0.29710776f * (float)dd);  // 10000^(-dd/31)
            const float ang = (float)ii * fr;
            const float c0 = cosf(ang), s0 = sinf(ang);
            float rlo = vlo * c0 - vhi * s0;
            float rhi = vhi * c0 + vlo * s0;
            if (which == 0) { rlo *= 0.125f; rhi *= 0.125f; }  // fold attn scale into Q
            ushort* dst = (which == 0) ? qo : ko;
            dst[off + dd]      = f2bf(rlo);
            dst[off + dd + 32] = f2bf(rhi);
          }
        }
      }
  } else {
#pragma unroll
    for (int m = 0; m < 4; ++m)
#pragma unroll
      for (int n = 0; n < 4; ++n)
#pragma unroll
        for (int r = 0; r < 4; ++r) {
          const int row = rb + m * 16 + g * 4 + r;
          const int col = cb + n * 16 + l15;
          float v = acc[m][n][r] + bias[col];
          if constexpr (EPI == 1) {
            v += resid[(size_t)row * N + col];
            outf[(size_t)row * N + col] = v;
          } else {
            const float ge = 0.5f * v * (1.0f + erff(v * 0.70710678f));
            outb[(size_t)row * N + col] = f2bf(ge);
          }
        }
  }
}

// ---------------------------------------------------------------- flash attention, swapped-QK^T
// 4 waves/block, each wave owns 16 q-rows (block = 64 q), KVBLK = 64.
// QK^T computed as mfma(K,Q) -> S^T: row=(g*4+r)=k, col=l15=q  => k-reduce is IN-LANE.
// Q pre-scaled 1/8 + RoPE'd. Vt: [B,H,64,T]. O: [B,T,H*64] bf16.
__global__ __launch_bounds__(256) void attn_k(const ushort* __restrict__ Q,
                                              const ushort* __restrict__ K,
                                              const ushort* __restrict__ Vt,
                                              ushort* __restrict__ O) {
  const int bh = blockIdx.x, qt = blockIdx.y;
  const int tid = threadIdx.x, wid = tid >> 6, lane = tid & 63;
  const int l15 = lane & 15, g = lane >> 4;
  const int q0 = qt * 64 + wid * 16;  // wave's q-base
  const size_t bho = (size_t)bh * (2048 * 64);
  const ushort* Qb = Q + bho;
  const ushort* Kb = K + bho;
  const ushort* Vb = Vt + bho;

  const bf16x8 qf0 = *(const bf16x8*)&Qb[(size_t)(q0 + l15) * 64 + g * 8];
  const bf16x8 qf1 = *(const bf16x8*)&Qb[(size_t)(q0 + l15) * 64 + 32 + g * 8];

  f32x4 o[4] = {};                     // PV acc: row=(g*4+r)=q, col=l15 (within d-frag nf)
  float m = -1e30f, l = 0.f;

  // per-wave P tile [16 q][64 k] bf16, stride 128B, XOR-swizzled (byte ^= (l15&7)<<4)
  __shared__ ushort pl[4][16 * 64];
  char* pbase = (char*)pl[wid];
  const int swz = (l15 & 7) << 4;

  const int nkt = qt + 1;
  for (int kt = 0; kt < nkt; ++kt) {
    const int k0 = kt * 64;
    f32x4 st[4];
#pragma unroll
    for (int sub = 0; sub < 4; ++sub) {
      const int kr = k0 + sub * 16 + l15;
      const bf16x8 kf0 = *(const bf16x8*)&Kb[(size_t)kr * 64 + g * 8];
      const bf16x8 kf1 = *(const bf16x8*)&Kb[(size_t)kr * 64 + 32 + g * 8];
      f32x4 z = {0.f, 0.f, 0.f, 0.f};
      f32x4 sv = __builtin_amdgcn_mfma_f32_16x16x32_bf16(kf0, qf0, z, 0, 0, 0);
      sv = __builtin_amdgcn_mfma_f32_16x16x32_bf16(kf1, qf1, sv, 0, 0, 0);
      st[sub] = sv;
    }
    if (k0 + 63 > q0) {  // diagonal tile: mask k > q (k = k0+sub*16+g*4+r, q = q0+l15)
#pragma unroll
      for (int sub = 0; sub < 4; ++sub) {
        const int kk = k0 + sub * 16 + g * 4;
#pragma unroll
        for (int r = 0; r < 4; ++r)
          if (kk + r > q0 + l15) st[sub][r] = -1e30f;
      }
    }
    // online softmax: all per-q state lives at lanes with l15 == q (replicated over g)
    float tm = st[0][0];
#pragma unroll
    for (int sub = 0; sub < 4; ++sub)
#pragma unroll
      for (int r = 0; r < 4; ++r) tm = fmaxf(tm, st[sub][r]);
    tm = fmaxf(tm, __shfl_xor(tm, 16));
    tm = fmaxf(tm, __shfl_xor(tm, 32));
    const float mnew = fmaxf(m, tm);
    const float corr = __expf(m - mnew);
    m = mnew;
    float ps = 0.f;
#pragma unroll
    for (int sub = 0; sub < 4; ++sub) {
      const float p0 = __expf(st[sub][0] - mnew);
      const float p1 = __expf(st[sub][1] - mnew);
      const float p2 = __expf(st[sub][2] - mnew);
      const float p3 = __expf(st[sub][3] - mnew);
      ps += (p0 + p1) + (p2 + p3);
      ushort4 pk;
      pk.x = f2bf(p0); pk.y = f2bf(p1); pk.z = f2bf(p2); pk.w = f2bf(p3);
      // P[q=l15][k=sub*16+g*4 .. +3]
      *(ushort4*)(pbase + ((l15 * 128 + ((sub * 32 + g * 8) ^ swz))))= pk;
    }
    ps += __shfl_xor(ps, 16);
    ps += __shfl_xor(ps, 32);
    l = l * corr + ps;
    // scale o (rows q = g*4+r) by corr(q) fetched from lane g*4+r
    float cr[4];
#pragma unroll
    for (int r = 0; r < 4; ++r) cr[r] = __shfl(corr, g * 4 + r);
#pragma unroll
    for (int nf = 0; nf < 4; ++nf)
#pragma unroll
      for (int r = 0; r < 4; ++r) o[nf][r] *= cr[r];
    __syncthreads();
    const bf16x8 pf0 = *(const bf16x8*)(pbase + (l15 * 128 + ((g * 16) ^ swz)));
    const bf16x8 pf1 = *(const bf16x8*)(pbase + (l15 * 128 + ((64 + g * 16) ^ swz)));
#pragma unroll
    for (int nf = 0; nf < 4; ++nf) {
      const ushort* vrow = &Vb[(size_t)(nf * 16 + l15) * 2048 + k0];
      const bf16x8 vf0 = *(const bf16x8*)(vrow + g * 8);
      const bf16x8 vf1 = *(const bf16x8*)(vrow + 32 + g * 8);
      o[nf] = __builtin_amdgcn_mfma_f32_16x16x32_bf16(pf0, vf0, o[nf], 0, 0, 0);
      o[nf] = __builtin_amdgcn_mfma_f32_16x16x32_bf16(pf1, vf1, o[nf], 0, 0, 0);
    }
    __syncthreads();
  }
  const float linv = 1.0f / l;
  float li[4];
#pragma unroll
  for (int r = 0; r < 4; ++r) li[r] = __shfl(linv, g * 4 + r);
  const int b = bh >> 4, h = bh & 15;
#pragma unroll
  for (int nf = 0; nf < 4; ++nf)
#pragma unroll
    for (int r = 0; r < 4; ++r) {
      const int qr = q0 + g * 4 + r;
      O[((size_t)(b * 2048 + qr)) * 1024 + h * 64 + nf * 16 + l15] = f2bf(o[nf][r] * li[r]);
    }
}

// ---------------------------------------------------------------- launcher
extern "C" void kernel_launch(void* const* d_in, const int* in_sizes, int n_in,
                              void* d_out, int out_size, void* d_ws, size_t ws_size,
                              hipStream_t stream) {
  const float* x      = (const float*)d_in[0];
  const float* w_qkv  = (const float*)d_in[2];
  const float* b_qkv  = (const float*)d_in[3];
  const float* w_proj = (const float*)d_in[4];
  const float* b_proj = (const float*)d_in[5];
  const float* g1     = (const float*)d_in[6];
  const float* be1    = (const float*)d_in[7];
  const float* g2     = (const float*)d_in[8];
  const float* be2    = (const float*)d_in[9];
  const float* w_mlp1 = (const float*)d_in[10];
  const float* b_mlp1 = (const float*)d_in[11];
  const float* w_mlp2 = (const float*)d_in[12];
  const float* b_mlp2 = (const float*)d_in[13];

  char* ws = (char*)d_ws;
  ushort* WQKVT  = (ushort*)(ws + 0);
  ushort* WPROJT = (ushort*)(ws + 6291456);
  ushort* WMLP1T = (ushort*)(ws + 8388608);
  ushort* WMLP2T = (ushort*)(ws + 16777216);
  ushort* H      = (ushort*)(ws + 25165824);
  ushort* Qs     = (ushort*)(ws + 41943040);
  ushort* Ks     = (ushort*)(ws + 58720256);
  ushort* Vn     = (ushort*)(ws + 75497472);
  ushort* Vt     = (ushort*)(ws + 92274688);
  ushort* M1     = (ushort*)(ws + 41943040);
  float*  X1     = (float*)(ws + 109051904);

  castT_k<<<dim3(3072 / 32, 1024 / 32), 256, 0, stream>>>(w_qkv, WQKVT, 1024, 3072);
  castT_k<<<dim3(1024 / 32, 1024 / 32), 256, 0, stream>>>(w_proj, WPROJT, 1024, 1024);
  castT_k<<<dim3(4096 / 32, 1024 / 32), 256, 0, stream>>>(w_mlp1, WMLP1T, 1024, 4096);
  castT_k<<<dim3(1024 / 32, 4096 / 32), 256, 0, stream>>>(w_mlp2, WMLP2T, 4096, 1024);

  ln_k<<<8192, 256, 0, stream>>>(x, g1, be1, H);

  gemm_k<0><<<dim3(3072 / 128, 8192 / 128), 256, 0, stream>>>(
      H, WQKVT, 8192, 3072, 1024, b_qkv, nullptr, nullptr, nullptr, Qs, Ks, Vn);

  vtrans_k<<<dim3(32, 64), 256, 0, stream>>>(Vn, Vt);

  attn_k<<<dim3(64, 32), 256, 0, stream>>>(Qs, Ks, Vt, H /* = O */);

  gemm_k<1><<<dim3(1024 / 128, 8192 / 128), 256, 0, stream>>>(
      H, WPROJT, 8192, 1024, 1024, b_proj, x, X1, nullptr, nullptr, nullptr, nullptr);

  ln_k<<<8192, 256, 0, stream>>>(X1, g2, be2, H /* = H2 */);

  gemm_k<2><<<dim3(4096 / 128, 8192 / 128), 256, 0, stream>>>(
      H, WMLP1T, 8192, 4096, 1024, b_mlp1, nullptr, nullptr, M1, nullptr, nullptr, nullptr);

  gemm_k<1><<<dim3(1024 / 128, 8192 / 128), 256, 0, stream>>>(
      M1, WMLP2T, 8192, 1024, 4096, b_mlp2, X1, (float*)d_out, nullptr, nullptr, nullptr, nullptr);
}

// Round 3
// 747.184 us; speedup vs baseline: 1.1556x; 1.0553x over previous
//
#include <hip/hip_runtime.h>

// ---------------------------------------------------------------- types
typedef __bf16  bf16x8 __attribute__((ext_vector_type(8)));
typedef float   f32x4  __attribute__((ext_vector_type(4)));

typedef const __attribute__((address_space(1))) void* gas_p;
typedef __attribute__((address_space(3))) void*       las_p;

__device__ __forceinline__ void glds16(const void* g, void* l) {
  // global -> LDS direct, 16B per lane; LDS dst is wave-uniform base + lane*16
  __builtin_amdgcn_global_load_lds((gas_p)g, (las_p)l, 16, 0, 0);
}

__device__ __forceinline__ ushort f2bf(float f) {  // RNE float->bf16
  unsigned u = __float_as_uint(f);
  u += 0x7fffu + ((u >> 16) & 1u);
  return (ushort)(u >> 16);
}

// ---------------------------------------------------------------- weight cast + transpose  w[K][N] f32 -> wT[N][K] bf16
__global__ __launch_bounds__(256) void castT_k(const float* __restrict__ w,
                                               ushort* __restrict__ wT,
                                               const int Kd, const int Nd) {
  __shared__ float t[32][33];
  const int nb = blockIdx.x * 32, kb = blockIdx.y * 32;
  const int tx = threadIdx.x & 31, ty = threadIdx.x >> 5;  // 32 x 8
#pragma unroll
  for (int r = 0; r < 32; r += 8)
    t[ty + r][tx] = w[(size_t)(kb + ty + r) * Nd + nb + tx];
  __syncthreads();
#pragma unroll
  for (int r = 0; r < 32; r += 8)
    wT[(size_t)(nb + ty + r) * Kd + kb + tx] = f2bf(t[tx][ty + r]);
}

// ---------------------------------------------------------------- LayerNorm (d=1024), fp32 in -> bf16 out
__global__ __launch_bounds__(256) void ln_k(const float* __restrict__ x,
                                            const float* __restrict__ gam,
                                            const float* __restrict__ bet,
                                            ushort* __restrict__ out) {
  const int row = blockIdx.x, tid = threadIdx.x;
  const float4 v = ((const float4*)(x + (size_t)row * 1024))[tid];
  float s  = v.x + v.y + v.z + v.w;
  float sq = v.x * v.x + v.y * v.y + v.z * v.z + v.w * v.w;
#pragma unroll
  for (int o = 32; o > 0; o >>= 1) { s += __shfl_xor(s, o); sq += __shfl_xor(sq, o); }
  __shared__ float red[8];
  const int wid = tid >> 6, lane = tid & 63;
  if (lane == 0) { red[wid] = s; red[4 + wid] = sq; }
  __syncthreads();
  s  = red[0] + red[1] + red[2] + red[3];
  sq = red[4] + red[5] + red[6] + red[7];
  const float mu   = s * (1.0f / 1024.0f);
  const float var  = sq * (1.0f / 1024.0f) - mu * mu;
  const float rstd = rsqrtf(var + 1e-5f);
  const float4 gv = ((const float4*)gam)[tid];
  const float4 bv = ((const float4*)bet)[tid];
  ushort4 o4;
  o4.x = f2bf((v.x - mu) * rstd * gv.x + bv.x);
  o4.y = f2bf((v.y - mu) * rstd * gv.y + bv.y);
  o4.z = f2bf((v.z - mu) * rstd * gv.z + bv.z);
  o4.w = f2bf((v.w - mu) * rstd * gv.w + bv.w);
  ((ushort4*)(out + (size_t)row * 1024))[tid] = o4;
}

// ---------------------------------------------------------------- V [B,H,T,64] -> Vt [B,H,64,T]  (bf16)
__global__ __launch_bounds__(256) void vtrans_k(const ushort* __restrict__ Vn,
                                                ushort* __restrict__ Vt) {
  const int bh = blockIdx.y, i0 = blockIdx.x * 64, tid = threadIdx.x;
  __shared__ ushort t[64][65];
  const ushort* src = Vn + (size_t)bh * (2048 * 64);
#pragma unroll
  for (int kk = 0; kk < 16; ++kk) {
    const int e = tid + kk * 256, r = e >> 6, c = e & 63;
    t[r][c] = src[(size_t)(i0 + r) * 64 + c];
  }
  __syncthreads();
  ushort* dst = Vt + (size_t)bh * (64 * 2048);
#pragma unroll
  for (int kk = 0; kk < 16; ++kk) {
    const int e = tid + kk * 256, r = e >> 6, c = e & 63;  // r = dh, c = i
    dst[(size_t)r * 2048 + i0 + c] = t[c][r];
  }
}

// ---------------------------------------------------------------- GEMM: A[M][K] bf16 x Bt[N][K] bf16 -> epilogue
// 128x128 tile, 4 waves (2x2), BK=32, global_load_lds staging (m97 structure).
template <int EPI>
__global__ __launch_bounds__(256) void gemm_k(
    const ushort* __restrict__ A, const ushort* __restrict__ Bt,
    const int M, const int N, const int K,
    const float* __restrict__ bias,
    const float* __restrict__ resid,
    float* __restrict__ outf,
    ushort* __restrict__ outb,
    ushort* __restrict__ qo, ushort* __restrict__ ko, ushort* __restrict__ vo) {
  __shared__ ushort lA[128 * 32];
  __shared__ ushort lB[128 * 32];
  const int tid = threadIdx.x;
  const int wid = tid >> 6, lane = tid & 63;
  const int l15 = lane & 15, g = lane >> 4;
  const int m0 = blockIdx.y * 128, n0 = blockIdx.x * 128;
  const int wm = wid >> 1, wn = wid & 1;

  const int srow = wid * 16 + (lane >> 2);
  const int scol = (lane & 3) * 8;
  const ushort* Ag0 = A + (size_t)(m0 + srow) * K + scol;
  const ushort* Ag1 = Ag0 + (size_t)64 * K;
  const ushort* Bg0 = Bt + (size_t)(n0 + srow) * K + scol;
  const ushort* Bg1 = Bg0 + (size_t)64 * K;
  ushort* lA0 = &lA[wid * 512];
  ushort* lA1 = &lA[(wid + 4) * 512];
  ushort* lB0 = &lB[wid * 512];
  ushort* lB1 = &lB[(wid + 4) * 512];

  const ushort* lar = &lA[(wm * 64 + l15) * 32 + g * 8];
  const ushort* lbr = &lB[(wn * 64 + l15) * 32 + g * 8];

  f32x4 acc[4][4] = {};

  for (int kt = 0; kt < K; kt += 32) {
    glds16(Ag0 + kt, lA0);
    glds16(Ag1 + kt, lA1);
    glds16(Bg0 + kt, lB0);
    glds16(Bg1 + kt, lB1);
    __syncthreads();
    bf16x8 af[4], bfr[4];
#pragma unroll
    for (int m = 0; m < 4; ++m) af[m] = *(const bf16x8*)(lar + m * 16 * 32);
#pragma unroll
    for (int n = 0; n < 4; ++n) bfr[n] = *(const bf16x8*)(lbr + n * 16 * 32);
#pragma unroll
    for (int m = 0; m < 4; ++m)
#pragma unroll
      for (int n = 0; n < 4; ++n)
        acc[m][n] = __builtin_amdgcn_mfma_f32_16x16x32_bf16(af[m], bfr[n], acc[m][n], 0, 0, 0);
    __syncthreads();
  }

  const int rb = m0 + wm * 64;
  const int cb = n0 + wn * 64;
  if constexpr (EPI == 0) {
    // QKV: c = which*1024 + h*64 + dd ; rope pairs (dd, dd+32) live in frags (n, n+2)
#pragma unroll
    for (int m = 0; m < 4; ++m)
#pragma unroll
      for (int r = 0; r < 4; ++r) {
        const int s = rb + m * 16 + g * 4 + r;
        const int bb = s >> 11, ii = s & 2047;
#pragma unroll
        for (int n = 0; n < 2; ++n) {
          const int c = cb + n * 16 + l15;
          const int which = c >> 10, h = (c >> 6) & 15, dd = c & 63;  // dd < 32
          const float vlo = acc[m][n][r] + bias[c];
          const float vhi = acc[m][n + 2][r] + bias[c + 32];
          const size_t off = ((size_t)((bb * 16 + h) * 2048 + ii)) * 64;
          if (which == 2) {
            vo[off + dd]      = f2bf(vlo);
            vo[off + dd + 32] = f2bf(vhi);
          } else {
            const float fr = __expf(-0.29710776f * (float)dd);  // 10000^(-dd/31)
            const float ang = (float)ii * fr;
            const float c0 = cosf(ang), s0 = sinf(ang);
            float rlo = vlo * c0 - vhi * s0;
            float rhi = vhi * c0 + vlo * s0;
            if (which == 0) { rlo *= 0.125f; rhi *= 0.125f; }  // fold attn scale into Q
            ushort* dst = (which == 0) ? qo : ko;
            dst[off + dd]      = f2bf(rlo);
            dst[off + dd + 32] = f2bf(rhi);
          }
        }
      }
  } else {
#pragma unroll
    for (int m = 0; m < 4; ++m)
#pragma unroll
      for (int n = 0; n < 4; ++n)
#pragma unroll
        for (int r = 0; r < 4; ++r) {
          const int row = rb + m * 16 + g * 4 + r;
          const int col = cb + n * 16 + l15;
          float v = acc[m][n][r] + bias[col];
          if constexpr (EPI == 1) {
            v += resid[(size_t)row * N + col];
            outf[(size_t)row * N + col] = v;
          } else {
            const float ge = 0.5f * v * (1.0f + erff(v * 0.70710678f));
            outb[(size_t)row * N + col] = f2bf(ge);
          }
        }
  }
}

// ---------------------------------------------------------------- flash attention, swapped-QK^T, v3
// 4 waves/block, wave owns 16 q-rows. Block processes q-tile PAIR (p, 31-p): 33 k-iters
// per block, perfectly balanced. NO barriers: P tile is wave-private (in-wave lgkmcnt
// ordering). Defer-max (T13, THR=8) skips o-rescale on most tiles.
// QK^T as mfma(K,Q) -> S^T: row=(g*4+r)=k, col=l15=q => k-reduce in-lane.
// Q pre-scaled 1/8 + RoPE'd. Vt: [B,H,64,T]. O: [B,T,H*64] bf16.
__global__ __launch_bounds__(256) void attn_k(const ushort* __restrict__ Q,
                                              const ushort* __restrict__ K,
                                              const ushort* __restrict__ Vt,
                                              ushort* __restrict__ O) {
  const int bh = blockIdx.x, pr = blockIdx.y;
  const int tid = threadIdx.x, wid = tid >> 6, lane = tid & 63;
  const int l15 = lane & 15, g = lane >> 4;
  const size_t bho = (size_t)bh * (2048 * 64);
  const ushort* Qb = Q + bho;
  const ushort* Kb = K + bho;
  const ushort* Vb = Vt + bho;
  const int b = bh >> 4, h = bh & 15;

  __shared__ ushort pl[4][16 * 64];   // per-wave P tile [16 q][64 k], XOR-swizzled
  char* pbase = (char*)pl[wid];
  const int swz = (l15 & 7) << 4;

#pragma unroll 1
  for (int half = 0; half < 2; ++half) {
    const int qt = half ? (31 - pr) : pr;
    const int q0 = qt * 64 + wid * 16;

    const bf16x8 qf0 = *(const bf16x8*)&Qb[(size_t)(q0 + l15) * 64 + g * 8];
    const bf16x8 qf1 = *(const bf16x8*)&Qb[(size_t)(q0 + l15) * 64 + 32 + g * 8];

    f32x4 o[4] = {};                  // PV acc: row=(g*4+r)=q, col=l15 (d-frag nf)
    float m = -1e30f, l = 0.f;

    const int nkt = qt + 1;
    for (int kt = 0; kt < nkt; ++kt) {
      const int k0 = kt * 64;
      f32x4 st[4];
#pragma unroll
      for (int sub = 0; sub < 4; ++sub) {
        const int kr = k0 + sub * 16 + l15;
        const bf16x8 kf0 = *(const bf16x8*)&Kb[(size_t)kr * 64 + g * 8];
        const bf16x8 kf1 = *(const bf16x8*)&Kb[(size_t)kr * 64 + 32 + g * 8];
        f32x4 z = {0.f, 0.f, 0.f, 0.f};
        f32x4 sv = __builtin_amdgcn_mfma_f32_16x16x32_bf16(kf0, qf0, z, 0, 0, 0);
        sv = __builtin_amdgcn_mfma_f32_16x16x32_bf16(kf1, qf1, sv, 0, 0, 0);
        st[sub] = sv;
      }
      if (k0 + 63 > q0) {  // diagonal tile: mask k > q (k = k0+sub*16+g*4+r, q = q0+l15)
#pragma unroll
        for (int sub = 0; sub < 4; ++sub) {
          const int kk = k0 + sub * 16 + g * 4;
#pragma unroll
          for (int r = 0; r < 4; ++r)
            if (kk + r > q0 + l15) st[sub][r] = -1e30f;
        }
      }
      // tile max: pairwise tree (4 parallel chains depth 3, then depth 2)
      f32x4 mv = st[0];
#pragma unroll
      for (int sub = 1; sub < 4; ++sub)
#pragma unroll
        for (int r = 0; r < 4; ++r) mv[r] = fmaxf(mv[r], st[sub][r]);
      float tm = fmaxf(fmaxf(mv[0], mv[1]), fmaxf(mv[2], mv[3]));
      tm = fmaxf(tm, __shfl_xor(tm, 16));
      tm = fmaxf(tm, __shfl_xor(tm, 32));
      // defer-max: only rescale when the running max grew by > 8
      if (!__all(tm - m <= 8.0f)) {
        const float mnew = fmaxf(m, tm);
        const float corr = __expf(m - mnew);
        m = mnew;
        l *= corr;
        float cr[4];
#pragma unroll
        for (int r = 0; r < 4; ++r) cr[r] = __shfl(corr, g * 4 + r);
#pragma unroll
        for (int nf = 0; nf < 4; ++nf)
#pragma unroll
          for (int r = 0; r < 4; ++r) o[nf][r] *= cr[r];
      }
      float ps = 0.f;
#pragma unroll
      for (int sub = 0; sub < 4; ++sub) {
        const float p0 = __expf(st[sub][0] - m);
        const float p1 = __expf(st[sub][1] - m);
        const float p2 = __expf(st[sub][2] - m);
        const float p3 = __expf(st[sub][3] - m);
        ps += (p0 + p1) + (p2 + p3);
        ushort4 pk;
        pk.x = f2bf(p0); pk.y = f2bf(p1); pk.z = f2bf(p2); pk.w = f2bf(p3);
        // P[q=l15][k=sub*16+g*4 .. +3]
        *(ushort4*)(pbase + ((l15 * 128 + ((sub * 32 + g * 8) ^ swz)))) = pk;
      }
      ps += __shfl_xor(ps, 16);
      ps += __shfl_xor(ps, 32);
      l += ps;
      // P re-read as PV A-frag (in-wave lgkmcnt ordering; no barrier needed)
      const bf16x8 pf0 = *(const bf16x8*)(pbase + (l15 * 128 + ((g * 16) ^ swz)));
      const bf16x8 pf1 = *(const bf16x8*)(pbase + (l15 * 128 + ((64 + g * 16) ^ swz)));
#pragma unroll
      for (int nf = 0; nf < 4; ++nf) {
        const ushort* vrow = &Vb[(size_t)(nf * 16 + l15) * 2048 + k0];
        const bf16x8 vf0 = *(const bf16x8*)(vrow + g * 8);
        const bf16x8 vf1 = *(const bf16x8*)(vrow + 32 + g * 8);
        o[nf] = __builtin_amdgcn_mfma_f32_16x16x32_bf16(pf0, vf0, o[nf], 0, 0, 0);
        o[nf] = __builtin_amdgcn_mfma_f32_16x16x32_bf16(pf1, vf1, o[nf], 0, 0, 0);
      }
    }
    const float linv = 1.0f / l;
    float li[4];
#pragma unroll
    for (int r = 0; r < 4; ++r) li[r] = __shfl(linv, g * 4 + r);
#pragma unroll
    for (int nf = 0; nf < 4; ++nf)
#pragma unroll
      for (int r = 0; r < 4; ++r) {
        const int qr = q0 + g * 4 + r;
        O[((size_t)(b * 2048 + qr)) * 1024 + h * 64 + nf * 16 + l15] = f2bf(o[nf][r] * li[r]);
      }
  }
}

// ---------------------------------------------------------------- launcher
extern "C" void kernel_launch(void* const* d_in, const int* in_sizes, int n_in,
                              void* d_out, int out_size, void* d_ws, size_t ws_size,
                              hipStream_t stream) {
  const float* x      = (const float*)d_in[0];
  const float* w_qkv  = (const float*)d_in[2];
  const float* b_qkv  = (const float*)d_in[3];
  const float* w_proj = (const float*)d_in[4];
  const float* b_proj = (const float*)d_in[5];
  const float* g1     = (const float*)d_in[6];
  const float* be1    = (const float*)d_in[7];
  const float* g2     = (const float*)d_in[8];
  const float* be2    = (const float*)d_in[9];
  const float* w_mlp1 = (const float*)d_in[10];
  const float* b_mlp1 = (const float*)d_in[11];
  const float* w_mlp2 = (const float*)d_in[12];
  const float* b_mlp2 = (const float*)d_in[13];

  char* ws = (char*)d_ws;
  ushort* WQKVT  = (ushort*)(ws + 0);
  ushort* WPROJT = (ushort*)(ws + 6291456);
  ushort* WMLP1T = (ushort*)(ws + 8388608);
  ushort* WMLP2T = (ushort*)(ws + 16777216);
  ushort* H      = (ushort*)(ws + 25165824);
  ushort* Qs     = (ushort*)(ws + 41943040);
  ushort* Ks     = (ushort*)(ws + 58720256);
  ushort* Vn     = (ushort*)(ws + 75497472);
  ushort* Vt     = (ushort*)(ws + 92274688);
  ushort* M1     = (ushort*)(ws + 41943040);
  float*  X1     = (float*)(ws + 109051904);

  castT_k<<<dim3(3072 / 32, 1024 / 32), 256, 0, stream>>>(w_qkv, WQKVT, 1024, 3072);
  castT_k<<<dim3(1024 / 32, 1024 / 32), 256, 0, stream>>>(w_proj, WPROJT, 1024, 1024);
  castT_k<<<dim3(4096 / 32, 1024 / 32), 256, 0, stream>>>(w_mlp1, WMLP1T, 1024, 4096);
  castT_k<<<dim3(1024 / 32, 4096 / 32), 256, 0, stream>>>(w_mlp2, WMLP2T, 4096, 1024);

  ln_k<<<8192, 256, 0, stream>>>(x, g1, be1, H);

  gemm_k<0><<<dim3(3072 / 128, 8192 / 128), 256, 0, stream>>>(
      H, WQKVT, 8192, 3072, 1024, b_qkv, nullptr, nullptr, nullptr, Qs, Ks, Vn);

  vtrans_k<<<dim3(32, 64), 256, 0, stream>>>(Vn, Vt);

  attn_k<<<dim3(64, 16), 256, 0, stream>>>(Qs, Ks, Vt, H /* = O */);

  gemm_k<1><<<dim3(1024 / 128, 8192 / 128), 256, 0, stream>>>(
      H, WPROJT, 8192, 1024, 1024, b_proj, x, X1, nullptr, nullptr, nullptr, nullptr);

  ln_k<<<8192, 256, 0, stream>>>(X1, g2, be2, H /* = H2 */);

  gemm_k<2><<<dim3(4096 / 128, 8192 / 128), 256, 0, stream>>>(
      H, WMLP1T, 8192, 4096, 1024, b_mlp1, nullptr, nullptr, M1, nullptr, nullptr, nullptr);

  gemm_k<1><<<dim3(1024 / 128, 8192 / 128), 256, 0, stream>>>(
      M1, WMLP2T, 8192, 1024, 4096, b_mlp2, X1, (float*)d_out, nullptr, nullptr, nullptr, nullptr);
}